// Round 8
// baseline (86.137 us; speedup 1.0000x reference)
//
#include <hip/hip_runtime.h>
#include <stdint.h>

typedef float f32x4 __attribute__((ext_vector_type(4)));
typedef uint32_t u32x4 __attribute__((ext_vector_type(4)));
typedef short s16x8 __attribute__((ext_vector_type(8)));

#define BB   8
#define NN   2048
#define FIN  128
#define FOUT 64

__device__ __forceinline__ uint32_t cvt_pk_bf16(float lo, float hi) {
  uint32_t r;
  asm("v_cvt_pk_bf16_f32 %0, %1, %2" : "=v"(r) : "v"(lo), "v"(hi));
  return r;
}

__device__ __forceinline__ s16x8 mk_s16x8(uint32_t a, uint32_t b, uint32_t c, uint32_t d) {
  union { uint32_t u[4]; s16x8 v; } x;
  x.u[0] = a; x.u[1] = b; x.u[2] = c; x.u[3] = d;
  return x.v;
}

// ---------------------------------------------------------------------------
// Kernel 1: R1 body (known-good) + XCD swizzle so XCD x writes batch x's hidT.
// ---------------------------------------------------------------------------
__global__ void k1_hidden(const float* __restrict__ h, const float* __restrict__ W,
                          const float* __restrict__ attw, ushort* __restrict__ hidT,
                          float* __restrict__ s1, float* __restrict__ s2) {
  __shared__ ushort wlds[FOUT * 136];   // W transposed, bf16, pitch 136 shorts
  const int tid = threadIdx.x;

  for (int idx = tid; idx < FIN * FOUT; idx += 256) {
    int k = idx >> 6, c = idx & 63;     // W row-major [k][c]
    wlds[c * 136 + k] = (ushort)(cvt_pk_bf16(W[idx], 0.f) & 0xffffu);
  }
  __syncthreads();

  const int bid = ((blockIdx.x & 7) << 5) | (blockIdx.x >> 3);

  const int lane = tid & 63, wid = tid >> 6;
  const int q = lane & 15, g = lane >> 4;
  const int wrow0 = bid * 64 + wid * 16;
  const int b  = wrow0 >> 11;
  const int n0 = wrow0 & (NN - 1);

  const float* hrow = h + (size_t)(wrow0 + q) * FIN + 8 * g;

  f32x4 acc[4];
  #pragma unroll
  for (int nt = 0; nt < 4; ++nt) acc[nt] = {0.f, 0.f, 0.f, 0.f};

  #pragma unroll
  for (int kk = 0; kk < 4; ++kk) {
    f32x4 h0 = *(const f32x4*)(hrow + 32 * kk);
    f32x4 h1 = *(const f32x4*)(hrow + 32 * kk + 4);
    s16x8 A = mk_s16x8(cvt_pk_bf16(h0[0], h0[1]), cvt_pk_bf16(h0[2], h0[3]),
                       cvt_pk_bf16(h1[0], h1[1]), cvt_pk_bf16(h1[2], h1[3]));
    #pragma unroll
    for (int nt = 0; nt < 4; ++nt) {
      s16x8 Bf = *(const s16x8*)(&wlds[(nt * 16 + q) * 136 + 32 * kk + 8 * g]);
      acc[nt] = __builtin_amdgcn_mfma_f32_16x16x32_bf16(A, Bf, acc[nt], 0, 0, 0);
    }
  }

  float a1v[4], a2v[4];
  #pragma unroll
  for (int nt = 0; nt < 4; ++nt) {
    a1v[nt] = attw[nt * 16 + q];
    a2v[nt] = attw[64 + nt * 16 + q];
  }
  float p1[4], p2[4];
  #pragma unroll
  for (int r = 0; r < 4; ++r) {
    float v1 = 0.f, v2 = 0.f;
    #pragma unroll
    for (int nt = 0; nt < 4; ++nt) { v1 += acc[nt][r] * a1v[nt]; v2 += acc[nt][r] * a2v[nt]; }
    #pragma unroll
    for (int m = 1; m < 16; m <<= 1) { v1 += __shfl_xor(v1, m, 64); v2 += __shfl_xor(v2, m, 64); }
    p1[r] = v1; p2[r] = v2;
  }
  if (q < 4) {
    int gr = wrow0 + 4 * g + q;
    float v1 = (q == 0) ? p1[0] : (q == 1) ? p1[1] : (q == 2) ? p1[2] : p1[3];
    float v2 = (q == 0) ? p2[0] : (q == 1) ? p2[1] : (q == 2) ? p2[2] : p2[3];
    s1[gr] = v1; s2[gr] = v2;
  }

  #pragma unroll
  for (int nt = 0; nt < 4; ++nt) {
    uint32_t lo = cvt_pk_bf16(acc[nt][0], acc[nt][1]);
    uint32_t hi = cvt_pk_bf16(acc[nt][2], acc[nt][3]);
    *(uint2*)(hidT + ((size_t)b * FOUT + nt * 16 + q) * NN + n0 + 4 * g) = make_uint2(lo, hi);
  }
}

// ---------------------------------------------------------------------------
// Kernel 2: occupancy-restructured. grid 2048 x 256thr, 8 blocks/CU.
// Block = 16 rows x 1024-j half; 4 waves x 256 j each, 8 k-steps.
// LDS: part (16KB) + partl only (s2 read from global: 8KB/batch, L1-hot).
// Writes unnormalized partial (1024 f32 + 16 lsum) to ws; k3 combines.
// ---------------------------------------------------------------------------
__global__ __launch_bounds__(256, 8) void k2_attn(
    const float* __restrict__ adj, const ushort* __restrict__ hidT,
    const float* __restrict__ s1, const float* __restrict__ s2,
    float* __restrict__ parts) {
  __shared__ float part[4][16][64];
  __shared__ float partl[4][16];

  const int tid = threadIdx.x;
  // XCD swizzle: 2048 blocks = 8 x 256; XCD x <- batch x.
  const int bid  = ((blockIdx.x & 7) << 8) | (blockIdx.x >> 3);
  const int b    = bid >> 8;
  const int rem  = bid & 255;
  const int it   = rem >> 1;          // i-tile 0..127
  const int half = rem & 1;           // j-half
  const int i0   = it << 4;

  const int lane = tid & 63, wid = tid >> 6;
  const int q = lane & 15, g = lane >> 4;
  const float s1r = s1[b * NN + i0 + q];
  const float* s2g = s2 + b * NN;

  const float*  adjrow = adj + (size_t)(b * NN + i0 + q) * NN;
  const ushort* hq     = hidT + ((size_t)b * FOUT + q) * NN;

  f32x4 acc0 = {0,0,0,0}, acc1 = {0,0,0,0}, acc2 = {0,0,0,0}, acc3 = {0,0,0,0};
  float lsum = 0.f;

  const int jbase = (half << 10) + wid * 256 + 8 * g;

  #pragma unroll
  for (int s = 0; s < 8; ++s) {
    const int j0 = jbase + 32 * s;
    f32x4 ca0 = *(const f32x4*)(adjrow + j0);
    f32x4 ca1 = *(const f32x4*)(adjrow + j0 + 4);
    f32x4 ct0 = *(const f32x4*)(s2g + j0);
    f32x4 ct1 = *(const f32x4*)(s2g + j0 + 4);
    u32x4 cb0 = *(const u32x4*)(hq + (size_t)0 * 16 * NN + j0);
    u32x4 cb1 = *(const u32x4*)(hq + (size_t)1 * 16 * NN + j0);
    u32x4 cb2 = *(const u32x4*)(hq + (size_t)2 * 16 * NN + j0);
    u32x4 cb3 = *(const u32x4*)(hq + (size_t)3 * 16 * NN + j0);

    // p = adj * exp(leakyrelu(s1+s2));  adj is exactly 0 or 1
    float e0 = s1r + ct0[0], e1 = s1r + ct0[1], e2 = s1r + ct0[2], e3 = s1r + ct0[3];
    float e4 = s1r + ct1[0], e5 = s1r + ct1[1], e6 = s1r + ct1[2], e7 = s1r + ct1[3];
    float p0 = ca0[0] * __expf(fmaxf(e0, 0.2f * e0));
    float p1 = ca0[1] * __expf(fmaxf(e1, 0.2f * e1));
    float p2 = ca0[2] * __expf(fmaxf(e2, 0.2f * e2));
    float p3 = ca0[3] * __expf(fmaxf(e3, 0.2f * e3));
    float p4 = ca1[0] * __expf(fmaxf(e4, 0.2f * e4));
    float p5 = ca1[1] * __expf(fmaxf(e5, 0.2f * e5));
    float p6 = ca1[2] * __expf(fmaxf(e6, 0.2f * e6));
    float p7 = ca1[3] * __expf(fmaxf(e7, 0.2f * e7));
    lsum += ((p0 + p1) + (p2 + p3)) + ((p4 + p5) + (p6 + p7));

    s16x8 A = mk_s16x8(cvt_pk_bf16(p0, p1), cvt_pk_bf16(p2, p3),
                       cvt_pk_bf16(p4, p5), cvt_pk_bf16(p6, p7));
    union { u32x4 u; s16x8 v; } w0, w1, w2, w3;
    w0.u = cb0; w1.u = cb1; w2.u = cb2; w3.u = cb3;
    acc0 = __builtin_amdgcn_mfma_f32_16x16x32_bf16(A, w0.v, acc0, 0, 0, 0);
    acc1 = __builtin_amdgcn_mfma_f32_16x16x32_bf16(A, w1.v, acc1, 0, 0, 0);
    acc2 = __builtin_amdgcn_mfma_f32_16x16x32_bf16(A, w2.v, acc2, 0, 0, 0);
    acc3 = __builtin_amdgcn_mfma_f32_16x16x32_bf16(A, w3.v, acc3, 0, 0, 0);
  }

  lsum += __shfl_xor(lsum, 16, 64);
  lsum += __shfl_xor(lsum, 32, 64);
  if (lane < 16) partl[wid][lane] = lsum;

  #pragma unroll
  for (int r = 0; r < 4; ++r) {
    part[wid][4 * g + r][ 0 + q] = acc0[r];
    part[wid][4 * g + r][16 + q] = acc1[r];
    part[wid][4 * g + r][32 + q] = acc2[r];
    part[wid][4 * g + r][48 + q] = acc3[r];
  }
  __syncthreads();

  // combine 4 waves -> one block partial; write to ws
  float* po = parts + (size_t)(b * 256 + rem) * 1040;
  #pragma unroll
  for (int q4 = 0; q4 < 4; ++q4) {
    int idx = tid + 256 * q4;
    int row = idx >> 6, col = idx & 63;
    po[idx] = (part[0][row][col] + part[1][row][col]) +
              (part[2][row][col] + part[3][row][col]);
  }
  if (tid < 16)
    po[1024 + tid] = (partl[0][tid] + partl[1][tid]) + (partl[2][tid] + partl[3][tid]);
}

// ---------------------------------------------------------------------------
// Kernel 3: combine 2 j-halves, normalize, ELU, write out.
// grid 1024 x 256thr; one i-tile per block.
// ---------------------------------------------------------------------------
__global__ __launch_bounds__(256, 8) void k3_combine(
    const float* __restrict__ parts, float* __restrict__ out) {
  const int tid = threadIdx.x;
  const int bid = ((blockIdx.x & 7) << 7) | (blockIdx.x >> 3);
  const int b  = bid >> 7;
  const int it = bid & 127;
  const int i0 = it << 4;

  const float* p0 = parts + (size_t)(b * 256 + it * 2) * 1040;
  const float* p1 = p0 + 1040;

  __shared__ float linv[16];
  if (tid < 16) linv[tid] = 1.f / (p0[1024 + tid] + p1[1024 + tid]);
  __syncthreads();

  #pragma unroll
  for (int q4 = 0; q4 < 4; ++q4) {
    int idx = tid + 256 * q4;
    int row = idx >> 6, col = idx & 63;
    float hp = (p0[idx] + p1[idx]) * linv[row];
    out[(size_t)(b * NN + i0 + row) * 64 + col] = (hp > 0.f) ? hp : expm1f(hp);
  }
}

extern "C" void kernel_launch(void* const* d_in, const int* in_sizes, int n_in,
                              void* d_out, int out_size, void* d_ws, size_t ws_size,
                              hipStream_t stream) {
  const float* h    = (const float*)d_in[0];
  const float* adj  = (const float*)d_in[1];
  const float* W    = (const float*)d_in[2];
  const float* attw = (const float*)d_in[3];
  float* out = (float*)d_out;

  char* ws = (char*)d_ws;
  ushort* hidT  = (ushort*)ws;                                  // 2 MB
  float*  s1    = (float*)(ws + (2u << 20));                    // 64 KB
  float*  s2    = (float*)(ws + (2u << 20) + (64u << 10));      // 64 KB
  float*  parts = (float*)(ws + (4u << 20));                    // 8.5 MB

  hipLaunchKernelGGL(k1_hidden, dim3(256), dim3(256), 0, stream, h, W, attw, hidT, s1, s2);
  hipLaunchKernelGGL(k2_attn, dim3(2048), dim3(256), 0, stream, adj, hidT, s1, s2, parts);
  hipLaunchKernelGGL(k3_combine, dim3(1024), dim3(256), 0, stream, parts, out);
}

// Round 9
// 63.043 us; speedup vs baseline: 1.3663x; 1.3663x over previous
//
#include <hip/hip_runtime.h>
#include <stdint.h>

typedef float f32x4 __attribute__((ext_vector_type(4)));
typedef uint32_t u32x4 __attribute__((ext_vector_type(4)));
typedef short s16x8 __attribute__((ext_vector_type(8)));

#define BB   8
#define NN   2048
#define FIN  128
#define FOUT 64

__device__ __forceinline__ uint32_t cvt_pk_bf16(float lo, float hi) {
  uint32_t r;
  asm("v_cvt_pk_bf16_f32 %0, %1, %2" : "=v"(r) : "v"(lo), "v"(hi));
  return r;
}

__device__ __forceinline__ s16x8 mk_s16x8(uint32_t a, uint32_t b, uint32_t c, uint32_t d) {
  union { uint32_t u[4]; s16x8 v; } x;
  x.u[0] = a; x.u[1] = b; x.u[2] = c; x.u[3] = d;
  return x.v;
}

// ---------------------------------------------------------------------------
// Kernel 1: R1 body (known-good) + XCD swizzle so XCD x writes batch x's hidT.
// ---------------------------------------------------------------------------
__global__ void k1_hidden(const float* __restrict__ h, const float* __restrict__ W,
                          const float* __restrict__ attw, ushort* __restrict__ hidT,
                          float* __restrict__ s1, float* __restrict__ s2) {
  __shared__ ushort wlds[FOUT * 136];   // W transposed, bf16, pitch 136 shorts
  const int tid = threadIdx.x;

  for (int idx = tid; idx < FIN * FOUT; idx += 256) {
    int k = idx >> 6, c = idx & 63;     // W row-major [k][c]
    wlds[c * 136 + k] = (ushort)(cvt_pk_bf16(W[idx], 0.f) & 0xffffu);
  }
  __syncthreads();

  const int bid = ((blockIdx.x & 7) << 5) | (blockIdx.x >> 3);

  const int lane = tid & 63, wid = tid >> 6;
  const int q = lane & 15, g = lane >> 4;
  const int wrow0 = bid * 64 + wid * 16;
  const int b  = wrow0 >> 11;
  const int n0 = wrow0 & (NN - 1);

  const float* hrow = h + (size_t)(wrow0 + q) * FIN + 8 * g;

  f32x4 acc[4];
  #pragma unroll
  for (int nt = 0; nt < 4; ++nt) acc[nt] = {0.f, 0.f, 0.f, 0.f};

  #pragma unroll
  for (int kk = 0; kk < 4; ++kk) {
    f32x4 h0 = *(const f32x4*)(hrow + 32 * kk);
    f32x4 h1 = *(const f32x4*)(hrow + 32 * kk + 4);
    s16x8 A = mk_s16x8(cvt_pk_bf16(h0[0], h0[1]), cvt_pk_bf16(h0[2], h0[3]),
                       cvt_pk_bf16(h1[0], h1[1]), cvt_pk_bf16(h1[2], h1[3]));
    #pragma unroll
    for (int nt = 0; nt < 4; ++nt) {
      s16x8 Bf = *(const s16x8*)(&wlds[(nt * 16 + q) * 136 + 32 * kk + 8 * g]);
      acc[nt] = __builtin_amdgcn_mfma_f32_16x16x32_bf16(A, Bf, acc[nt], 0, 0, 0);
    }
  }

  float a1v[4], a2v[4];
  #pragma unroll
  for (int nt = 0; nt < 4; ++nt) {
    a1v[nt] = attw[nt * 16 + q];
    a2v[nt] = attw[64 + nt * 16 + q];
  }
  float p1[4], p2[4];
  #pragma unroll
  for (int r = 0; r < 4; ++r) {
    float v1 = 0.f, v2 = 0.f;
    #pragma unroll
    for (int nt = 0; nt < 4; ++nt) { v1 += acc[nt][r] * a1v[nt]; v2 += acc[nt][r] * a2v[nt]; }
    #pragma unroll
    for (int m = 1; m < 16; m <<= 1) { v1 += __shfl_xor(v1, m, 64); v2 += __shfl_xor(v2, m, 64); }
    p1[r] = v1; p2[r] = v2;
  }
  if (q < 4) {
    int gr = wrow0 + 4 * g + q;
    float v1 = (q == 0) ? p1[0] : (q == 1) ? p1[1] : (q == 2) ? p1[2] : p1[3];
    float v2 = (q == 0) ? p2[0] : (q == 1) ? p2[1] : (q == 2) ? p2[2] : p2[3];
    s1[gr] = v1; s2[gr] = v2;
  }

  #pragma unroll
  for (int nt = 0; nt < 4; ++nt) {
    uint32_t lo = cvt_pk_bf16(acc[nt][0], acc[nt][1]);
    uint32_t hi = cvt_pk_bf16(acc[nt][2], acc[nt][3]);
    *(uint2*)(hidT + ((size_t)b * FOUT + nt * 16 + q) * NN + n0 + 4 * g) = make_uint2(lo, hi);
  }
}

// ---------------------------------------------------------------------------
// Kernel 2: 8-wave blocks (512 thr), grid 1024, j split 8-ways (8 steps/wave).
// R7 per-wave body (s2l staged, plain loads, __expf), no launch_bounds.
// LDS ~41KB -> 3 blocks/CU = 24 waves/CU (75% occ) with R7-level per-wave ILP.
// ---------------------------------------------------------------------------
__global__ void k2_attn(
    const float* __restrict__ adj, const ushort* __restrict__ hidT,
    const float* __restrict__ s1, const float* __restrict__ s2,
    float* __restrict__ out) {
  __shared__ float s2l[NN];
  __shared__ float part[8][16][64];
  __shared__ float partl[8][16];

  const int tid = threadIdx.x;
  // XCD swizzle: 1024 blocks; XCD x <- contiguous 128 = batch x.
  const int bid = ((blockIdx.x & 7) << 7) | (blockIdx.x >> 3);
  const int b  = bid >> 7;
  const int i0 = (bid & 127) << 4;

  {
    const f32x4* src = (const f32x4*)(s2 + b * NN);
    f32x4* dst = (f32x4*)s2l;
    for (int idx = tid; idx < NN / 4; idx += 512) dst[idx] = src[idx];
  }
  __syncthreads();

  const int lane = tid & 63, wid = tid >> 6;   // wid 0..7
  const int q = lane & 15, g = lane >> 4;
  const float s1r = s1[b * NN + i0 + q];

  const float*  adjrow = adj + (size_t)(b * NN + i0 + q) * NN;
  const ushort* hq     = hidT + ((size_t)b * FOUT + q) * NN;

  f32x4 acc0 = {0,0,0,0}, acc1 = {0,0,0,0}, acc2 = {0,0,0,0}, acc3 = {0,0,0,0};
  float lsum = 0.f;

  const int jbase = wid * 256 + 8 * g;

  #pragma unroll
  for (int s = 0; s < 8; ++s) {
    const int j0 = jbase + 32 * s;
    f32x4 ca0 = *(const f32x4*)(adjrow + j0);
    f32x4 ca1 = *(const f32x4*)(adjrow + j0 + 4);
    f32x4 ct0 = *(const f32x4*)(s2l + j0);
    f32x4 ct1 = *(const f32x4*)(s2l + j0 + 4);
    u32x4 cb0 = *(const u32x4*)(hq + (size_t)0 * 16 * NN + j0);
    u32x4 cb1 = *(const u32x4*)(hq + (size_t)1 * 16 * NN + j0);
    u32x4 cb2 = *(const u32x4*)(hq + (size_t)2 * 16 * NN + j0);
    u32x4 cb3 = *(const u32x4*)(hq + (size_t)3 * 16 * NN + j0);

    // p = adj * exp(leakyrelu(s1+s2));  adj is exactly 0 or 1
    float e0 = s1r + ct0[0], e1 = s1r + ct0[1], e2 = s1r + ct0[2], e3 = s1r + ct0[3];
    float e4 = s1r + ct1[0], e5 = s1r + ct1[1], e6 = s1r + ct1[2], e7 = s1r + ct1[3];
    float p0 = ca0[0] * __expf(fmaxf(e0, 0.2f * e0));
    float p1 = ca0[1] * __expf(fmaxf(e1, 0.2f * e1));
    float p2 = ca0[2] * __expf(fmaxf(e2, 0.2f * e2));
    float p3 = ca0[3] * __expf(fmaxf(e3, 0.2f * e3));
    float p4 = ca1[0] * __expf(fmaxf(e4, 0.2f * e4));
    float p5 = ca1[1] * __expf(fmaxf(e5, 0.2f * e5));
    float p6 = ca1[2] * __expf(fmaxf(e6, 0.2f * e6));
    float p7 = ca1[3] * __expf(fmaxf(e7, 0.2f * e7));
    lsum += ((p0 + p1) + (p2 + p3)) + ((p4 + p5) + (p6 + p7));

    s16x8 A = mk_s16x8(cvt_pk_bf16(p0, p1), cvt_pk_bf16(p2, p3),
                       cvt_pk_bf16(p4, p5), cvt_pk_bf16(p6, p7));
    union { u32x4 u; s16x8 v; } w0, w1, w2, w3;
    w0.u = cb0; w1.u = cb1; w2.u = cb2; w3.u = cb3;
    acc0 = __builtin_amdgcn_mfma_f32_16x16x32_bf16(A, w0.v, acc0, 0, 0, 0);
    acc1 = __builtin_amdgcn_mfma_f32_16x16x32_bf16(A, w1.v, acc1, 0, 0, 0);
    acc2 = __builtin_amdgcn_mfma_f32_16x16x32_bf16(A, w2.v, acc2, 0, 0, 0);
    acc3 = __builtin_amdgcn_mfma_f32_16x16x32_bf16(A, w3.v, acc3, 0, 0, 0);
  }

  // reduce row-sums over the 4 g-groups, stash per-wave partials
  lsum += __shfl_xor(lsum, 16, 64);
  lsum += __shfl_xor(lsum, 32, 64);
  if (lane < 16) partl[wid][lane] = lsum;

  #pragma unroll
  for (int r = 0; r < 4; ++r) {
    part[wid][4 * g + r][ 0 + q] = acc0[r];
    part[wid][4 * g + r][16 + q] = acc1[r];
    part[wid][4 * g + r][32 + q] = acc2[r];
    part[wid][4 * g + r][48 + q] = acc3[r];
  }
  __syncthreads();

  // combine 8 waves; 1024 outputs, 512 threads -> 2 each
  #pragma unroll
  for (int q4 = 0; q4 < 2; ++q4) {
    int idx = tid + 512 * q4;
    int row = idx >> 6, col = idx & 63;
    float v  = ((part[0][row][col] + part[1][row][col]) +
                (part[2][row][col] + part[3][row][col])) +
               ((part[4][row][col] + part[5][row][col]) +
                (part[6][row][col] + part[7][row][col]));
    float li = ((partl[0][row] + partl[1][row]) + (partl[2][row] + partl[3][row])) +
               ((partl[4][row] + partl[5][row]) + (partl[6][row] + partl[7][row]));
    float hp = v / li;
    out[(size_t)(b * NN + i0 + row) * 64 + col] = (hp > 0.f) ? hp : expm1f(hp);
  }
}

extern "C" void kernel_launch(void* const* d_in, const int* in_sizes, int n_in,
                              void* d_out, int out_size, void* d_ws, size_t ws_size,
                              hipStream_t stream) {
  const float* h    = (const float*)d_in[0];
  const float* adj  = (const float*)d_in[1];
  const float* W    = (const float*)d_in[2];
  const float* attw = (const float*)d_in[3];
  float* out = (float*)d_out;

  char* ws = (char*)d_ws;
  ushort* hidT = (ushort*)ws;                                   // 2 MB
  float*  s1   = (float*)(ws + (2u << 20));                     // 64 KB
  float*  s2   = (float*)(ws + (2u << 20) + (64u << 10));       // 64 KB

  hipLaunchKernelGGL(k1_hidden, dim3(256), dim3(256), 0, stream, h, W, attw, hidT, s1, s2);
  hipLaunchKernelGGL(k2_attn, dim3(BB * (NN / 16)), dim3(512), 0, stream, adj, hidT, s1, s2, out);
}

// Round 10
// 54.976 us; speedup vs baseline: 1.5668x; 1.1467x over previous
//
#include <hip/hip_runtime.h>
#include <stdint.h>

typedef float f32x4 __attribute__((ext_vector_type(4)));
typedef uint32_t u32x4 __attribute__((ext_vector_type(4)));
typedef short s16x8 __attribute__((ext_vector_type(8)));

#define BB   8
#define NN   2048
#define FIN  128
#define FOUT 64
#define JT   256          // adj tile width (floats) = 1KB burst per row
#define NTIL (NN / JT)    // 8 tiles

__device__ __forceinline__ uint32_t cvt_pk_bf16(float lo, float hi) {
  uint32_t r;
  asm("v_cvt_pk_bf16_f32 %0, %1, %2" : "=v"(r) : "v"(lo), "v"(hi));
  return r;
}

__device__ __forceinline__ s16x8 mk_s16x8(uint32_t a, uint32_t b, uint32_t c, uint32_t d) {
  union { uint32_t u[4]; s16x8 v; } x;
  x.u[0] = a; x.u[1] = b; x.u[2] = c; x.u[3] = d;
  return x.v;
}

// ---------------------------------------------------------------------------
// Kernel 1: R1 body (known-good) + XCD swizzle so XCD x writes batch x's hidT.
// ---------------------------------------------------------------------------
__global__ void k1_hidden(const float* __restrict__ h, const float* __restrict__ W,
                          const float* __restrict__ attw, ushort* __restrict__ hidT,
                          float* __restrict__ s1, float* __restrict__ s2) {
  __shared__ ushort wlds[FOUT * 136];   // W transposed, bf16, pitch 136 shorts
  const int tid = threadIdx.x;

  for (int idx = tid; idx < FIN * FOUT; idx += 256) {
    int k = idx >> 6, c = idx & 63;     // W row-major [k][c]
    wlds[c * 136 + k] = (ushort)(cvt_pk_bf16(W[idx], 0.f) & 0xffffu);
  }
  __syncthreads();

  const int bid = ((blockIdx.x & 7) << 5) | (blockIdx.x >> 3);

  const int lane = tid & 63, wid = tid >> 6;
  const int q = lane & 15, g = lane >> 4;
  const int wrow0 = bid * 64 + wid * 16;
  const int b  = wrow0 >> 11;
  const int n0 = wrow0 & (NN - 1);

  const float* hrow = h + (size_t)(wrow0 + q) * FIN + 8 * g;

  f32x4 acc[4];
  #pragma unroll
  for (int nt = 0; nt < 4; ++nt) acc[nt] = {0.f, 0.f, 0.f, 0.f};

  #pragma unroll
  for (int kk = 0; kk < 4; ++kk) {
    f32x4 h0 = *(const f32x4*)(hrow + 32 * kk);
    f32x4 h1 = *(const f32x4*)(hrow + 32 * kk + 4);
    s16x8 A = mk_s16x8(cvt_pk_bf16(h0[0], h0[1]), cvt_pk_bf16(h0[2], h0[3]),
                       cvt_pk_bf16(h1[0], h1[1]), cvt_pk_bf16(h1[2], h1[3]));
    #pragma unroll
    for (int nt = 0; nt < 4; ++nt) {
      s16x8 Bf = *(const s16x8*)(&wlds[(nt * 16 + q) * 136 + 32 * kk + 8 * g]);
      acc[nt] = __builtin_amdgcn_mfma_f32_16x16x32_bf16(A, Bf, acc[nt], 0, 0, 0);
    }
  }

  float a1v[4], a2v[4];
  #pragma unroll
  for (int nt = 0; nt < 4; ++nt) {
    a1v[nt] = attw[nt * 16 + q];
    a2v[nt] = attw[64 + nt * 16 + q];
  }
  float p1[4], p2[4];
  #pragma unroll
  for (int r = 0; r < 4; ++r) {
    float v1 = 0.f, v2 = 0.f;
    #pragma unroll
    for (int nt = 0; nt < 4; ++nt) { v1 += acc[nt][r] * a1v[nt]; v2 += acc[nt][r] * a2v[nt]; }
    #pragma unroll
    for (int m = 1; m < 16; m <<= 1) { v1 += __shfl_xor(v1, m, 64); v2 += __shfl_xor(v2, m, 64); }
    p1[r] = v1; p2[r] = v2;
  }
  if (q < 4) {
    int gr = wrow0 + 4 * g + q;
    float v1 = (q == 0) ? p1[0] : (q == 1) ? p1[1] : (q == 2) ? p1[2] : p1[3];
    float v2 = (q == 0) ? p2[0] : (q == 1) ? p2[1] : (q == 2) ? p2[2] : p2[3];
    s1[gr] = v1; s2[gr] = v2;
  }

  #pragma unroll
  for (int nt = 0; nt < 4; ++nt) {
    uint32_t lo = cvt_pk_bf16(acc[nt][0], acc[nt][1]);
    uint32_t hi = cvt_pk_bf16(acc[nt][2], acc[nt][3]);
    *(uint2*)(hidT + ((size_t)b * FOUT + nt * 16 + q) * NN + n0 + 4 * g) = make_uint2(lo, hi);
  }
}

// ---------------------------------------------------------------------------
// Kernel 2 v3: adj staged through LDS in 16x256 tiles (1KB contiguous burst
// per row visit, reg-staged, double-buffered, XOR-swizzled reads).
// 256 thr / 4 waves; per tile each wave owns 64 j-cols (2 k-steps of 32).
// part[] combine aliases atile buf0 (dead after the k-loop).
// ---------------------------------------------------------------------------
__global__ void k2_attn(
    const float* __restrict__ adj, const ushort* __restrict__ hidT,
    const float* __restrict__ s1, const float* __restrict__ s2,
    float* __restrict__ out) {
  // LDS layout (aliased):
  //   [0,16384)      atile buf0  (16 rows x 256 f32)   | part[4][16][64] after loop
  //   [16384,32768)  atile buf1
  //   [32768,40960)  s2l[2048]
  //   [40960,41216)  partl[4][16]
  __shared__ __align__(16) char smem[41216];
  float* s2l   = (float*)(smem + 32768);
  float* partl = (float*)(smem + 40960);

  const int tid = threadIdx.x;
  // XCD swizzle: 1024 blocks; XCD x <- contiguous 128 = batch x.
  const int bid = ((blockIdx.x & 7) << 7) | (blockIdx.x >> 3);
  const int b  = bid >> 7;
  const int i0 = (bid & 127) << 4;

  const int lane = tid & 63, wid = tid >> 6;
  const int q = lane & 15, g = lane >> 4;

  // stage s2 (8KB) once
  {
    const f32x4* src = (const f32x4*)(s2 + b * NN);
    f32x4* dst = (f32x4*)s2l;
    #pragma unroll
    for (int it = 0; it < 2; ++it) dst[tid + 256 * it] = src[tid + 256 * it];
  }

  const float s1r = s1[b * NN + i0 + q];
  const float*  adjrow0 = adj + (size_t)(b * NN + i0) * NN;   // row 0 of tile
  const ushort* hq      = hidT + ((size_t)b * FOUT + q) * NN;

  f32x4 acc0 = {0,0,0,0}, acc1 = {0,0,0,0}, acc2 = {0,0,0,0}, acc3 = {0,0,0,0};
  float lsum = 0.f;

  // ---- staging helpers (each wave stages rows 4*wid .. 4*wid+3) ----
  const int r0 = wid << 2;
  f32x4 srg0, srg1, srg2, srg3;

  #define LOAD_TILE(jt) do {                                                   \
    const float* gb = adjrow0 + (size_t)(jt) * JT + (lane << 2);               \
    srg0 = *(const f32x4*)(gb + (size_t)(r0 + 0) * NN);                        \
    srg1 = *(const f32x4*)(gb + (size_t)(r0 + 1) * NN);                        \
    srg2 = *(const f32x4*)(gb + (size_t)(r0 + 2) * NN);                        \
    srg3 = *(const f32x4*)(gb + (size_t)(r0 + 3) * NN);                        \
  } while (0)

  #define DSW_TILE(bb) do {                                                    \
    char* db = smem + ((bb) << 14);                                            \
    *(f32x4*)(db + ((r0 + 0) << 10) + ((lane << 4) ^ (((r0 + 0) & 7) << 4))) = srg0; \
    *(f32x4*)(db + ((r0 + 1) << 10) + ((lane << 4) ^ (((r0 + 1) & 7) << 4))) = srg1; \
    *(f32x4*)(db + ((r0 + 2) << 10) + ((lane << 4) ^ (((r0 + 2) & 7) << 4))) = srg2; \
    *(f32x4*)(db + ((r0 + 3) << 10) + ((lane << 4) ^ (((r0 + 3) & 7) << 4))) = srg3; \
  } while (0)

  // prologue: stage tile 0
  LOAD_TILE(0);
  DSW_TILE(0);
  __syncthreads();

  const int swz = (q & 7) << 4;

  #pragma unroll
  for (int t = 0; t < NTIL; ++t) {
    if (t + 1 < NTIL) LOAD_TILE(t + 1);     // issue early; lands during compute

    const char* tb = smem + ((t & 1) << 14);
    #pragma unroll
    for (int s = 0; s < 2; ++s) {
      const int jloc = (wid << 6) + (g << 3) + (s << 5);   // 0..255
      const int j0g  = t * JT + jloc;                       // global col
      const int lin  = (q << 10) + (jloc << 2);             // byte in tile

      f32x4 ca0 = *(const f32x4*)(tb + ((lin     ) ^ swz));
      f32x4 ca1 = *(const f32x4*)(tb + ((lin + 16) ^ swz));
      f32x4 ct0 = *(const f32x4*)(s2l + j0g);
      f32x4 ct1 = *(const f32x4*)(s2l + j0g + 4);
      u32x4 cb0 = *(const u32x4*)(hq + (size_t)0 * 16 * NN + j0g);
      u32x4 cb1 = *(const u32x4*)(hq + (size_t)1 * 16 * NN + j0g);
      u32x4 cb2 = *(const u32x4*)(hq + (size_t)2 * 16 * NN + j0g);
      u32x4 cb3 = *(const u32x4*)(hq + (size_t)3 * 16 * NN + j0g);

      // p = adj * exp(leakyrelu(s1+s2));  adj is exactly 0 or 1
      float e0 = s1r + ct0[0], e1 = s1r + ct0[1], e2 = s1r + ct0[2], e3 = s1r + ct0[3];
      float e4 = s1r + ct1[0], e5 = s1r + ct1[1], e6 = s1r + ct1[2], e7 = s1r + ct1[3];
      float p0 = ca0[0] * __expf(fmaxf(e0, 0.2f * e0));
      float p1 = ca0[1] * __expf(fmaxf(e1, 0.2f * e1));
      float p2 = ca0[2] * __expf(fmaxf(e2, 0.2f * e2));
      float p3 = ca0[3] * __expf(fmaxf(e3, 0.2f * e3));
      float p4 = ca1[0] * __expf(fmaxf(e4, 0.2f * e4));
      float p5 = ca1[1] * __expf(fmaxf(e5, 0.2f * e5));
      float p6 = ca1[2] * __expf(fmaxf(e6, 0.2f * e6));
      float p7 = ca1[3] * __expf(fmaxf(e7, 0.2f * e7));
      lsum += ((p0 + p1) + (p2 + p3)) + ((p4 + p5) + (p6 + p7));

      s16x8 A = mk_s16x8(cvt_pk_bf16(p0, p1), cvt_pk_bf16(p2, p3),
                         cvt_pk_bf16(p4, p5), cvt_pk_bf16(p6, p7));
      union { u32x4 u; s16x8 v; } w0, w1, w2, w3;
      w0.u = cb0; w1.u = cb1; w2.u = cb2; w3.u = cb3;
      acc0 = __builtin_amdgcn_mfma_f32_16x16x32_bf16(A, w0.v, acc0, 0, 0, 0);
      acc1 = __builtin_amdgcn_mfma_f32_16x16x32_bf16(A, w1.v, acc1, 0, 0, 0);
      acc2 = __builtin_amdgcn_mfma_f32_16x16x32_bf16(A, w2.v, acc2, 0, 0, 0);
      acc3 = __builtin_amdgcn_mfma_f32_16x16x32_bf16(A, w3.v, acc3, 0, 0, 0);
    }

    if (t + 1 < NTIL) DSW_TILE((t + 1) & 1); // write-late (T14)
    __syncthreads();
  }

  // reduce row-sums over the 4 g-groups, stash per-wave partials
  lsum += __shfl_xor(lsum, 16, 64);
  lsum += __shfl_xor(lsum, 32, 64);
  if (lane < 16) partl[wid * 16 + lane] = lsum;

  // part aliases atile buf0 (all k-loop reads done: final barrier above)
  float* part = (float*)smem;   // [4][16][64]
  #pragma unroll
  for (int r = 0; r < 4; ++r) {
    part[(wid * 16 + 4 * g + r) * 64 +  0 + q] = acc0[r];
    part[(wid * 16 + 4 * g + r) * 64 + 16 + q] = acc1[r];
    part[(wid * 16 + 4 * g + r) * 64 + 32 + q] = acc2[r];
    part[(wid * 16 + 4 * g + r) * 64 + 48 + q] = acc3[r];
  }
  __syncthreads();

  #pragma unroll
  for (int q4 = 0; q4 < 4; ++q4) {
    int idx = tid + 256 * q4;
    int row = idx >> 6, col = idx & 63;
    float v  = (part[(0 * 16 + row) * 64 + col] + part[(1 * 16 + row) * 64 + col]) +
               (part[(2 * 16 + row) * 64 + col] + part[(3 * 16 + row) * 64 + col]);
    float li = (partl[0 * 16 + row] + partl[1 * 16 + row]) +
               (partl[2 * 16 + row] + partl[3 * 16 + row]);
    float hp = v / li;
    out[(size_t)(b * NN + i0 + row) * 64 + col] = (hp > 0.f) ? hp : expm1f(hp);
  }
}

extern "C" void kernel_launch(void* const* d_in, const int* in_sizes, int n_in,
                              void* d_out, int out_size, void* d_ws, size_t ws_size,
                              hipStream_t stream) {
  const float* h    = (const float*)d_in[0];
  const float* adj  = (const float*)d_in[1];
  const float* W    = (const float*)d_in[2];
  const float* attw = (const float*)d_in[3];
  float* out = (float*)d_out;

  char* ws = (char*)d_ws;
  ushort* hidT = (ushort*)ws;                                   // 2 MB
  float*  s1   = (float*)(ws + (2u << 20));                     // 64 KB
  float*  s2   = (float*)(ws + (2u << 20) + (64u << 10));       // 64 KB

  hipLaunchKernelGGL(k1_hidden, dim3(256), dim3(256), 0, stream, h, W, attw, hidT, s1, s2);
  hipLaunchKernelGGL(k2_attn, dim3(BB * (NN / 16)), dim3(256), 0, stream, adj, hidT, s1, s2, out);
}